// Round 9
// baseline (215.375 us; speedup 1.0000x reference)
//
#include <hip/hip_runtime.h>
#include <math.h>

#define KNN 64

typedef unsigned long long u64;

// Value pipeline (bitwise-verified vs harness np ref; r2/r3/r6/r7/r8 absmax=0):
//   csq = (x0^2+x2^2) + (x1^2+x3^2)   (noFMA butterfly; fp contract OFF)
//   dot = asc-k FMA chain
//   d2  = fmaf(-2, dot, sqx+csq)
// Keys: u64 (transformed_d2_bits<<32 | local_idx) — unique; ascending u64 order
// == required tie order. Ballot in float domain (no NaN, no -0.0 possible).
//
// r9: r7/r8's regression was LDS WRITE THROUGHPUT (4096 unconditional trash
// ds_write_b64/wave = ~16K LDS-clk vs r6's ~450 masked writes), not bank
// conflicts (r8: 10x the conflicts of r7, same runtime) and not the batched
// bookkeeping. This round: r6's zero-waste stores + one capacity check per
// 256-candidate group + ONE-GROUP-AHEAD REGISTER PREFETCH of coords+csq so
// the next group's global/LDS loads overlap the current group's ballot chain
// and flush work. Flush machinery byte-identical to r8 (all HW-verified).

template<int CTRL>
__device__ __forceinline__ unsigned dpp32(unsigned v) {
    return (unsigned)__builtin_amdgcn_update_dpp((int)v, (int)v, CTRL, 0xF, 0xF, false);
}

// Cross-lane exchange of a u64 with partner lane^J.
template<int J>
__device__ __forceinline__ u64 kv_exch(u64 kv, int addr32) {
    unsigned lo = (unsigned)kv, hi = (unsigned)(kv >> 32);
    unsigned rlo, rhi;
    if constexpr (J == 1) {            // quad_perm [1,0,3,2] (HW-verified)
        rlo = dpp32<0xB1>(lo); rhi = dpp32<0xB1>(hi);
    } else if constexpr (J == 2) {     // quad_perm [2,3,0,1] (HW-verified)
        rlo = dpp32<0x4E>(lo); rhi = dpp32<0x4E>(hi);
    } else if constexpr (J == 4) {     // l^7(half_mirror) ∘ l^1 ∘ l^2 = l^4 (HW-verified)
        rlo = dpp32<0x4E>(dpp32<0xB1>(dpp32<0x141>(lo)));
        rhi = dpp32<0x4E>(dpp32<0xB1>(dpp32<0x141>(hi)));
    } else if constexpr (J == 8) {     // row_ror:8 == xor8 (HW-verified)
        rlo = dpp32<0x128>(lo); rhi = dpp32<0x128>(hi);
    } else if constexpr (J == 16) {    // ds_swizzle xor-mode (r3-verified)
        rlo = (unsigned)__builtin_amdgcn_ds_swizzle((int)lo, (16 << 10) | 0x1F);
        rhi = (unsigned)__builtin_amdgcn_ds_swizzle((int)hi, (16 << 10) | 0x1F);
    } else {                           // J == 32: ds_bpermute (r3-verified)
        rlo = (unsigned)__builtin_amdgcn_ds_bpermute(addr32, (int)lo);
        rhi = (unsigned)__builtin_amdgcn_ds_bpermute(addr32, (int)hi);
    }
    return ((u64)rhi << 32) | (u64)rlo;
}

// One bitonic compare-exchange stage: partner = lane^J, block size K.
template<int K, int J>
__device__ __forceinline__ void ce(u64 &kv, int lane, int addr32) {
    const u64 r = kv_exch<J>(kv, addr32);
    const bool tm = ((lane & K) == 0) == ((lane & J) == 0);
    kv = ((kv < r) == tm) ? kv : r;
}

__device__ __forceinline__ void clean64(u64 &kv, int lane, int addr32) {
    ce<64,32>(kv, lane, addr32);
    ce<64,16>(kv, lane, addr32);
    ce<64, 8>(kv, lane, addr32);
    ce<64, 4>(kv, lane, addr32);
    ce<64, 2>(kv, lane, addr32);
    ce<64, 1>(kv, lane, addr32);
}

__device__ __forceinline__ u64 sort64(u64 kv, int lane, int addr32) {
    ce<2,1>(kv, lane, addr32);
    ce<4,2>(kv, lane, addr32);   ce<4,1>(kv, lane, addr32);
    ce<8,4>(kv, lane, addr32);   ce<8,2>(kv, lane, addr32);   ce<8,1>(kv, lane, addr32);
    ce<16,8>(kv, lane, addr32);  ce<16,4>(kv, lane, addr32);  ce<16,2>(kv, lane, addr32);  ce<16,1>(kv, lane, addr32);
    ce<32,16>(kv, lane, addr32); ce<32,8>(kv, lane, addr32);  ce<32,4>(kv, lane, addr32);  ce<32,2>(kv, lane, addr32);  ce<32,1>(kv, lane, addr32);
    clean64(kv, lane, addr32);
    return kv;
}

#define PAD_RAW 0x7F800000FFFFFFFFull   // raw:+inf bits, idx:~0 -> transforms to u64 max

// Flush: transform raw buffer -> sort keys, bitonic sort, reversal-merge into
// the sorted list, clean, tighten worst_f, reset buffer to pad.
__device__ __forceinline__ void flush_merge(u64 &kv, float &worst_f,
                                            u64* __restrict__ s_buf,
                                            int lane, int addr32, int addr63) {
    const u64 raw = s_buf[lane];
    unsigned hi = (unsigned)(raw >> 32);
    hi ^= (unsigned)((int)hi >> 31) | 0x80000000u;           // order-preserving
    u64 kvb = ((u64)hi << 32) | (unsigned)raw;
    kvb = sort64(kvb, lane, addr32);
    // reversal-merge: kv[i] = min(list[i], buf_sorted[63-i]) -> bitonic
    const unsigned rlo = (unsigned)__builtin_amdgcn_ds_bpermute(addr63, (int)(unsigned)kvb);
    const unsigned rhi = (unsigned)__builtin_amdgcn_ds_bpermute(addr63, (int)(unsigned)(kvb >> 32));
    const u64 r = ((u64)rhi << 32) | (u64)rlo;
    kv = (r < kv) ? r : kv;
    clean64(kv, lane, addr32);
    unsigned w = (unsigned)__builtin_amdgcn_readlane((int)(unsigned)(kv >> 32), 63);
    w ^= (w & 0x80000000u) ? 0x80000000u : 0xFFFFFFFFu;      // untransform (pad -> +inf)
    worst_f = __uint_as_float(w);
    s_buf[lane] = PAD_RAW;
}

__global__ __launch_bounds__(256) void knn_wave_kernel(
    const float4* __restrict__ coords,
    float* __restrict__ outIdx,
    float* __restrict__ outDist,
    int S, int Nq)
{
#pragma clang fp contract(off)
    extern __shared__ u64 smem_u64[];              // [S/2] csq floats + 4*64 u64 buf
    float* __restrict__ s_csq = (float*)smem_u64;

    const int tid   = threadIdx.x;
    const int lane  = tid & 63;
    const int wid   = tid >> 6;
    const int qbase = blockIdx.x << 2;             // 4 queries/block, same segment
    const int seg_start = (qbase / S) * S;         // S % 4 == 0 (S=4096)

    // ---- cooperative csq fill (identical butterfly, contract off) ----
    for (int p = tid; p < S; p += 256) {
        const float4 c = coords[seg_start + p];
        s_csq[p] = (c.x * c.x + c.z * c.z) + (c.y * c.y + c.w * c.w);
    }
    __syncthreads();

    const int q = qbase + wid;
    if (q >= Nq) return;                           // wave-uniform, after sync

    u64* __restrict__ s_buf = smem_u64 + (S >> 1) + (wid << 6);  // 64 slots/wave
    const float4* __restrict__ seg = coords + seg_start;

    const float4 x = coords[q];
    const float sqx = (x.x * x.x + x.z * x.z) + (x.y * x.y + x.w * x.w);

    const int addr32 = (lane ^ 32) << 2;
    const int addr63 = (lane ^ 63) << 2;

    u64 kv = 0xFF800000FFFFFFFFull;                // all-pad sorted list (transformed)
    float worst_f = __builtin_inff();
    s_buf[lane] = PAD_RAW;
    int bufcnt = 0;

    const int S4 = S & ~255;                       // main: 4 chunks per iteration

    // ---- software pipeline: prefetch group 0 ----
    float4 pc[4]; float pcsq[4];
#pragma unroll
    for (int u = 0; u < 4; ++u) {
        const int j = (u << 6) + lane;
        pc[u]   = seg[j];
        pcsq[u] = s_csq[j];
    }

    for (int c0 = 0; c0 < S4; c0 += 256) {
        // consume prefetched group
        float4 cc[4]; float ccsq[4];
#pragma unroll
        for (int u = 0; u < 4; ++u) { cc[u] = pc[u]; ccsq[u] = pcsq[u]; }

        // issue next group's loads NOW (overlap with ballot chain + flush)
        if (c0 + 256 < S4) {
#pragma unroll
            for (int u = 0; u < 4; ++u) {
                const int j = c0 + 256 + (u << 6) + lane;
                pc[u]   = seg[j];
                pcsq[u] = s_csq[j];
            }
        }

        // ---- distances + ballots for all 4 sub-chunks (ILP) ----
        float d2v[4];
        u64 mv[4];
#pragma unroll
        for (int u = 0; u < 4; ++u) {
            const float4 c = cc[u];
            const float dot = __builtin_fmaf(x.w, c.w,
                              __builtin_fmaf(x.z, c.z,
                              __builtin_fmaf(x.y, c.y, x.x * c.x)));
            d2v[u] = __builtin_fmaf(-2.0f, dot, sqx + ccsq[u]);
            mv[u]  = __ballot(d2v[u] < worst_f);
        }
        const int p0 = __popcll(mv[0]), p1 = __popcll(mv[1]);
        const int p2 = __popcll(mv[2]), p3 = __popcll(mv[3]);
        const int cnt4 = p0 + p1 + p2 + p3;

        if (bufcnt + cnt4 <= 64) {
            // ---- fast path: one capacity check; survivor-only masked stores ----
            const int bases[4] = {bufcnt, bufcnt + p0, bufcnt + p0 + p1,
                                  bufcnt + p0 + p1 + p2};
#pragma unroll
            for (int u = 0; u < 4; ++u) {
                if (mv[u]) {                       // skip empty sub-chunks
                    const int pos = __builtin_amdgcn_mbcnt_hi(
                                        (unsigned)(mv[u] >> 32),
                                        __builtin_amdgcn_mbcnt_lo((unsigned)mv[u], bases[u]));
                    if (d2v[u] < worst_f)          // exec-masked store, no waste
                        s_buf[pos] = ((u64)__float_as_uint(d2v[u]) << 32)
                                   | (unsigned)(c0 + (u << 6) + lane);
                }
            }
            bufcnt += cnt4;
        } else {
            // ---- careful path: exact r6 per-sub-chunk logic ----
#pragma unroll
            for (int u = 0; u < 4; ++u) {
                bool surv = d2v[u] < worst_f;
                u64 m = mv[u];
                int cnt = __popcll(m);
                if (bufcnt + cnt > 64) {           // wave-uniform
                    flush_merge(kv, worst_f, s_buf, lane, addr32, addr63);
                    bufcnt = 0;
                    surv = d2v[u] < worst_f;       // re-ballot vs tightened worst
                    m = __ballot(surv);
                    cnt = __popcll(m);
                }
                if (m) {
                    const int pos = __builtin_amdgcn_mbcnt_hi(
                                        (unsigned)(m >> 32),
                                        __builtin_amdgcn_mbcnt_lo((unsigned)m, bufcnt));
                    if (surv)
                        s_buf[pos] = ((u64)__float_as_uint(d2v[u]) << 32)
                                   | (unsigned)(c0 + (u << 6) + lane);
                    bufcnt += cnt;
                }
            }
        }
    }
    for (int c0 = S4; c0 < S; c0 += 64) {          // generic tail (S%256!=0 safety)
        const int j = c0 + lane;
        const float4 c = seg[j];
        const float csq = s_csq[j];
        const float dot = __builtin_fmaf(x.w, c.w,
                          __builtin_fmaf(x.z, c.z,
                          __builtin_fmaf(x.y, c.y, x.x * c.x)));
        const float d2  = __builtin_fmaf(-2.0f, dot, sqx + csq);
        bool surv = d2 < worst_f;
        u64 m = __ballot(surv);
        int cnt = __popcll(m);
        if (bufcnt + cnt > 64) {
            flush_merge(kv, worst_f, s_buf, lane, addr32, addr63);
            bufcnt = 0;
            surv = d2 < worst_f;
            m = __ballot(surv);
            cnt = __popcll(m);
        }
        if (m) {
            const int pos = __builtin_amdgcn_mbcnt_hi(
                                (unsigned)(m >> 32),
                                __builtin_amdgcn_mbcnt_lo((unsigned)m, bufcnt));
            if (surv)
                s_buf[pos] = ((u64)__float_as_uint(d2) << 32) | (unsigned)j;
            bufcnt += cnt;
        }
    }

    if (bufcnt > 0)
        flush_merge(kv, worst_f, s_buf, lane, addr32, addr63);

    // lane l holds rank l: fully coalesced 64-wide stores
    const unsigned idxs = (unsigned)kv;
    unsigned bk = (unsigned)(kv >> 32);
    bk ^= ((bk & 0x80000000u) ? 0x80000000u : 0xFFFFFFFFu);  // undo transform
    const float d2 = __uint_as_float(bk);
    outIdx [(size_t)q * KNN + lane] = (float)(seg_start + (int)idxs);
    outDist[(size_t)q * KNN + lane] = fmaxf(d2, 0.0f);
}

extern "C" void kernel_launch(void* const* d_in, const int* in_sizes, int n_in,
                              void* d_out, int out_size, void* d_ws, size_t ws_size,
                              hipStream_t stream) {
    const float* coords = (const float*)d_in[1];
    const int N = in_sizes[1] / 4;
    const int B = in_sizes[2] - 1;
    const int S = N / B;
    (void)n_in; (void)d_ws; (void)ws_size; (void)out_size;

    float* outIdx  = (float*)d_out;
    float* outDist = outIdx + (size_t)N * KNN;

    const int blocks = (N + 3) / 4;                // 4 waves (queries) per block
    const size_t smem = (size_t)S * 4 + 4 * 64 * 8;  // csq + 4 wave buffers
    knn_wave_kernel<<<blocks, 256, smem, stream>>>((const float4*)coords,
                                                   outIdx, outDist, S, N);
}

// Round 10
// 186.370 us; speedup vs baseline: 1.1556x; 1.1556x over previous
//
#include <hip/hip_runtime.h>
#include <math.h>

#define KNN 64

typedef unsigned long long u64;

// Value pipeline (bitwise-verified vs harness np ref; r2/r3/r6 absmax=0) — UNCHANGED:
//   csq = (x0^2+x2^2) + (x1^2+x3^2)   (noFMA butterfly; fp contract OFF)
//   dot = asc-k FMA chain
//   d2  = fmaf(-2, dot, sqx+csq)
// Keys: u64 (transformed_d2_bits<<32 | local_idx) — unique; ascending u64 order
// == required tie order. Ballot in float domain (no NaN, no -0.0 possible).
//
// r10 = EXACT REVERT to r6 (best measured: 151 µs kernel / 184 µs bench).
// Falsified perturbations (keep for the record, do not retry):
//   r3  scan-VALU cut            -> null (DS latency masked VALU then)
//   r7  batched + same-addr trash-> -25 µs (LDS write-storm, 223K conflicts)
//   r8  batched + per-lane trash -> -25 µs (LDS write THROUGHPUT, not conflicts)
//   r9  batched + reg prefetch   -> -36 µs (live-range/VGPR pressure, occ 75->58)
// r6 structure: csq table in LDS; survivor buffer + ballot/mbcnt compaction;
// flush = transform + bitonic sort64 + reversal-merge + clean64 with exchanges
// J=1(0xB1 quad_perm), J=2(0x4E), J=8(row_ror:8) on VALU DPP (HW-verified),
// J=4,16 ds_swizzle, J=32 ds_bpermute (HW-verified r1-r3).

template<int CTRL>
__device__ __forceinline__ unsigned dpp32(unsigned v) {
    return (unsigned)__builtin_amdgcn_update_dpp((int)v, (int)v, CTRL, 0xF, 0xF, false);
}

// Cross-lane exchange of a u64 with partner lane^J.
// J in {1,2,8}: VALU DPP (direction-proof patterns only).
// J in {4,16}: ds_swizzle xor-mode (r3-verified). J=32: ds_bpermute (r3-verified).
template<int J>
__device__ __forceinline__ u64 kv_exch(u64 kv, int addr32) {
    unsigned lo = (unsigned)kv, hi = (unsigned)(kv >> 32);
    unsigned rlo, rhi;
    if constexpr (J == 1) {            // quad_perm [1,0,3,2], self-inverse
        rlo = dpp32<0xB1>(lo); rhi = dpp32<0xB1>(hi);
    } else if constexpr (J == 2) {     // quad_perm [2,3,0,1], self-inverse
        rlo = dpp32<0x4E>(lo); rhi = dpp32<0x4E>(hi);
    } else if constexpr (J == 8) {     // row_ror:8 == xor8 (symmetric)
        rlo = dpp32<0x128>(lo); rhi = dpp32<0x128>(hi);
    } else if constexpr (J == 4 || J == 16) {
        rlo = (unsigned)__builtin_amdgcn_ds_swizzle((int)lo, (J << 10) | 0x1F);
        rhi = (unsigned)__builtin_amdgcn_ds_swizzle((int)hi, (J << 10) | 0x1F);
    } else {                           // J == 32
        rlo = (unsigned)__builtin_amdgcn_ds_bpermute(addr32, (int)lo);
        rhi = (unsigned)__builtin_amdgcn_ds_bpermute(addr32, (int)hi);
    }
    return ((u64)rhi << 32) | (u64)rlo;
}

// One bitonic compare-exchange stage: partner = lane^J, block size K.
template<int K, int J>
__device__ __forceinline__ void ce(u64 &kv, int lane, int addr32) {
    const u64 r = kv_exch<J>(kv, addr32);
    const bool tm = ((lane & K) == 0) == ((lane & J) == 0);
    kv = ((kv < r) == tm) ? kv : r;
}

__device__ __forceinline__ void clean64(u64 &kv, int lane, int addr32) {
    ce<64,32>(kv, lane, addr32);
    ce<64,16>(kv, lane, addr32);
    ce<64, 8>(kv, lane, addr32);
    ce<64, 4>(kv, lane, addr32);
    ce<64, 2>(kv, lane, addr32);
    ce<64, 1>(kv, lane, addr32);
}

__device__ __forceinline__ u64 sort64(u64 kv, int lane, int addr32) {
    ce<2,1>(kv, lane, addr32);
    ce<4,2>(kv, lane, addr32);   ce<4,1>(kv, lane, addr32);
    ce<8,4>(kv, lane, addr32);   ce<8,2>(kv, lane, addr32);   ce<8,1>(kv, lane, addr32);
    ce<16,8>(kv, lane, addr32);  ce<16,4>(kv, lane, addr32);  ce<16,2>(kv, lane, addr32);  ce<16,1>(kv, lane, addr32);
    ce<32,16>(kv, lane, addr32); ce<32,8>(kv, lane, addr32);  ce<32,4>(kv, lane, addr32);  ce<32,2>(kv, lane, addr32);  ce<32,1>(kv, lane, addr32);
    clean64(kv, lane, addr32);
    return kv;
}

#define PAD_RAW 0x7F800000FFFFFFFFull   // raw:+inf bits, idx:~0 -> transforms to u64 max

// Flush: transform raw buffer -> sort keys, bitonic sort, reversal-merge into
// the sorted list, clean, tighten worst_f, reset buffer to pad.
__device__ __forceinline__ void flush_merge(u64 &kv, float &worst_f,
                                            u64* __restrict__ s_buf,
                                            int lane, int addr32, int addr63) {
    const u64 raw = s_buf[lane];
    unsigned hi = (unsigned)(raw >> 32);
    hi ^= (unsigned)((int)hi >> 31) | 0x80000000u;           // order-preserving
    u64 kvb = ((u64)hi << 32) | (unsigned)raw;
    kvb = sort64(kvb, lane, addr32);
    // reversal-merge: kv[i] = min(list[i], buf_sorted[63-i]) -> bitonic
    const unsigned rlo = (unsigned)__builtin_amdgcn_ds_bpermute(addr63, (int)(unsigned)kvb);
    const unsigned rhi = (unsigned)__builtin_amdgcn_ds_bpermute(addr63, (int)(unsigned)(kvb >> 32));
    const u64 r = ((u64)rhi << 32) | (u64)rlo;
    kv = (r < kv) ? r : kv;
    clean64(kv, lane, addr32);
    unsigned w = (unsigned)__builtin_amdgcn_readlane((int)(unsigned)(kv >> 32), 63);
    w ^= (w & 0x80000000u) ? 0x80000000u : 0xFFFFFFFFu;      // untransform (pad -> +inf)
    worst_f = __uint_as_float(w);
    s_buf[lane] = PAD_RAW;
}

__global__ __launch_bounds__(256) void knn_wave_kernel(
    const float4* __restrict__ coords,
    float* __restrict__ outIdx,
    float* __restrict__ outDist,
    int S, int Nq)
{
#pragma clang fp contract(off)
    extern __shared__ u64 smem_u64[];              // [S/2] csq floats + 4*64 u64 buf
    float* __restrict__ s_csq = (float*)smem_u64;

    const int tid   = threadIdx.x;
    const int lane  = tid & 63;
    const int wid   = tid >> 6;
    const int qbase = blockIdx.x << 2;             // 4 queries/block, same segment
    const int seg_start = (qbase / S) * S;         // S % 4 == 0 (S=4096)

    // ---- cooperative csq fill (identical butterfly, contract off) ----
    for (int p = tid; p < S; p += 256) {
        const float4 c = coords[seg_start + p];
        s_csq[p] = (c.x * c.x + c.z * c.z) + (c.y * c.y + c.w * c.w);
    }
    __syncthreads();

    const int q = qbase + wid;
    if (q >= Nq) return;                           // wave-uniform, after sync

    u64* __restrict__ s_buf = smem_u64 + (S >> 1) + (wid << 6);  // 64 slots/wave
    const float4* __restrict__ seg = coords + seg_start;

    const float4 x = coords[q];
    const float sqx = (x.x * x.x + x.z * x.z) + (x.y * x.y + x.w * x.w);

    const int addr32 = (lane ^ 32) << 2;
    const int addr63 = (lane ^ 63) << 2;

    u64 kv = 0xFF800000FFFFFFFFull;                // all-pad sorted list (transformed)
    float worst_f = __builtin_inff();
    s_buf[lane] = PAD_RAW;
    int bufcnt = 0;

    const int S4 = S & ~255;                       // main: 4 chunks per iteration
    for (int c0 = 0; c0 < S4; c0 += 256) {
#pragma unroll
        for (int u = 0; u < 4; ++u) {
            const int base = c0 + (u << 6);
            const int j = base + lane;
            const float4 c = seg[j];               // imm-offset foldable (±4KB)
            const float csq = s_csq[j];
            const float dot = __builtin_fmaf(x.w, c.w,
                              __builtin_fmaf(x.z, c.z,
                              __builtin_fmaf(x.y, c.y, x.x * c.x)));
            const float d2  = __builtin_fmaf(-2.0f, dot, sqx + csq);

            bool surv = d2 < worst_f;              // float order == key order here
            u64 m = __ballot(surv);
            int cnt = __popcll(m);
            if (bufcnt + cnt > 64) {               // wave-uniform
                flush_merge(kv, worst_f, s_buf, lane, addr32, addr63);
                bufcnt = 0;
                surv = d2 < worst_f;               // re-ballot vs tightened worst
                m = __ballot(surv);
                cnt = __popcll(m);
            }
            if (m) {                               // skip empty chunks (wave-uniform)
                const int pos = __builtin_amdgcn_mbcnt_hi(
                                    (unsigned)(m >> 32),
                                    __builtin_amdgcn_mbcnt_lo((unsigned)m, bufcnt));
                if (surv)
                    s_buf[pos] = ((u64)__float_as_uint(d2) << 32) | (unsigned)j;
                bufcnt += cnt;
            }
        }
    }
    for (int c0 = S4; c0 < S; c0 += 64) {          // generic tail (S%256!=0 safety)
        const int j = c0 + lane;
        const float4 c = seg[j];
        const float csq = s_csq[j];
        const float dot = __builtin_fmaf(x.w, c.w,
                          __builtin_fmaf(x.z, c.z,
                          __builtin_fmaf(x.y, c.y, x.x * c.x)));
        const float d2  = __builtin_fmaf(-2.0f, dot, sqx + csq);
        bool surv = d2 < worst_f;
        u64 m = __ballot(surv);
        int cnt = __popcll(m);
        if (bufcnt + cnt > 64) {
            flush_merge(kv, worst_f, s_buf, lane, addr32, addr63);
            bufcnt = 0;
            surv = d2 < worst_f;
            m = __ballot(surv);
            cnt = __popcll(m);
        }
        if (m) {
            const int pos = __builtin_amdgcn_mbcnt_hi(
                                (unsigned)(m >> 32),
                                __builtin_amdgcn_mbcnt_lo((unsigned)m, bufcnt));
            if (surv)
                s_buf[pos] = ((u64)__float_as_uint(d2) << 32) | (unsigned)j;
            bufcnt += cnt;
        }
    }

    if (bufcnt > 0)
        flush_merge(kv, worst_f, s_buf, lane, addr32, addr63);

    // lane l holds rank l: fully coalesced 64-wide stores
    const unsigned idxs = (unsigned)kv;
    unsigned bk = (unsigned)(kv >> 32);
    bk ^= ((bk & 0x80000000u) ? 0x80000000u : 0xFFFFFFFFu);  // undo transform
    const float d2 = __uint_as_float(bk);
    outIdx [(size_t)q * KNN + lane] = (float)(seg_start + (int)idxs);
    outDist[(size_t)q * KNN + lane] = fmaxf(d2, 0.0f);
}

extern "C" void kernel_launch(void* const* d_in, const int* in_sizes, int n_in,
                              void* d_out, int out_size, void* d_ws, size_t ws_size,
                              hipStream_t stream) {
    const float* coords = (const float*)d_in[1];
    const int N = in_sizes[1] / 4;
    const int B = in_sizes[2] - 1;
    const int S = N / B;
    (void)n_in; (void)d_ws; (void)ws_size; (void)out_size;

    float* outIdx  = (float*)d_out;
    float* outDist = outIdx + (size_t)N * KNN;

    const int blocks = (N + 3) / 4;                // 4 waves (queries) per block
    const size_t smem = (size_t)S * 4 + 4 * 64 * 8;  // csq + 4 wave buffers
    knn_wave_kernel<<<blocks, 256, smem, stream>>>((const float4*)coords,
                                                   outIdx, outDist, S, N);
}